// Round 12
// baseline (578.593 us; speedup 1.0000x reference)
//
#include <hip/hip_runtime.h>
#include <hip/hip_fp16.h>
#include <hip/hip_cooperative_groups.h>

namespace cg = cooperative_groups;

#define A     96
#define DET0  256
#define NZ    32
#define NY    256
#define NX    256
#define T     256
#define NC    8
#define LAMB  0.01f

// ws layout (floats):
//   trig  : [A][2]            @ 0        (192, padded to 256; padding zeroed — it
//                                         absorbs the harmless -128B zero-weight tap)
//   res_t : [A][DET0][NZ]     @ 256      (786,432) fp32, seeded -p_perm in phase 1
//   vol_h : [NY][NX][NZ] f16  @ 786,688  (2,097,152 ushorts)
//   part  : [NC][A][DET0][NZ] @ 1,835,264 (fp32)
#define TRIG_OFF  0
#define REST_OFF  256
#define VOLB_OFF  786688
#define PART_OFF  1835264
#define RES_ELEMS 786432

// acc += f16half(v) * w, forced v_fma_mix_f32.
__device__ __forceinline__ void accp_mix(float& a0, float& a1, unsigned v, float w) {
    asm("v_fma_mix_f32 %0, %2, %3, %0 op_sel:[0,0,0] op_sel_hi:[1,0,0]\n\t"
        "v_fma_mix_f32 %1, %2, %3, %1 op_sel:[1,0,0] op_sel_hi:[1,0,0]"
        : "+v"(a0), "+v"(a1)
        : "v"(v), "v"(w));
}
__device__ __forceinline__ void acc8h(float* acc, uint4 q, float w) {
    accp_mix(acc[0], acc[1], q.x, w);
    accp_mix(acc[2], acc[3], q.y, w);
    accp_mix(acc[4], acc[5], q.z, w);
    accp_mix(acc[6], acc[7], q.w, w);
}

// ---------------------------------------------------------------------------
__device__ __forceinline__ void rng(float g, float b, float L, float H,
                                    float& lo, float& hi) {
    if (fabsf(g) > 1e-5f) {
        float r0 = (L - b) / g, r1 = (H - b) / g;
        lo = fminf(r0, r1); hi = fmaxf(r0, r1);
    } else {
        bool in = (b >= L && b <= H);
        lo = in ? -1e9f : 1e9f;
        hi = in ? 1e9f : -1e9f;
    }
}
__device__ __forceinline__ int clampi(float v) {
    return (int)fminf(fmaxf(v, -2.f), 258.f);
}

__device__ __forceinline__ void sample_edge(const char* base, float ix, float iy,
                                            float* acc) {
    float xf = floorf(ix), yf = floorf(iy);
    float fx = ix - xf, fy = iy - yf;
    int x0 = (int)xf, y0 = (int)yf;
    float wx0 = 1.f - fx, wx1 = fx, wy0 = 1.f - fy, wy1 = fy;
    if ((unsigned)x0 >= NX)       wx0 = 0.f;
    if ((unsigned)(x0 + 1) >= NX) wx1 = 0.f;
    if ((unsigned)y0 >= NY)       wy0 = 0.f;
    if ((unsigned)(y0 + 1) >= NY) wy1 = 0.f;
    if ((wx0 == 0.f && wx1 == 0.f) || (wy0 == 0.f && wy1 == 0.f)) return;
    int cx0 = min(max(x0, 0), NX - 1);
    int cx1 = min(max(x0 + 1, 0), NX - 1);
    int cy0 = min(max(y0, 0), NY - 1);
    int cy1 = min(max(y0 + 1, 0), NY - 1);
    uint4 q00 = *(const uint4*)(base + ((size_t)((cy0 << 8) + cx0) << 6));
    uint4 q01 = *(const uint4*)(base + ((size_t)((cy0 << 8) + cx1) << 6));
    uint4 q10 = *(const uint4*)(base + ((size_t)((cy1 << 8) + cx0) << 6));
    uint4 q11 = *(const uint4*)(base + ((size_t)((cy1 << 8) + cx1) << 6));
    acc8h(acc, q00, wy0 * wx0);
    acc8h(acc, q01, wy0 * wx1);
    acc8h(acc, q10, wy1 * wx0);
    acc8h(acc, q11, wy1 * wx1);
}

// ---------------------------------------------------------------------------
// Fused pipeline: one cooperative kernel, grid.sync() between phases.
// Eliminates ~3 inter-kernel launch gaps (~10-12 us each, per cross-round ledger).
// Phase bodies are byte-identical to the proven round-10 kernels.
// grid 1024 x 256; __launch_bounds__(256,4) guarantees 4 blocks/CU co-residency.
__global__ __launch_bounds__(256, 4) void k_fused(const float* __restrict__ src,
                                                  const float* __restrict__ p,
                                                  float* __restrict__ out,
                                                  float* __restrict__ ws) {
    __shared__ float smem[64 * 33];     // phase 1 transpose/seed; phase 4 ob staging
    cg::grid_group grid = cg::this_grid();
    const int bid = blockIdx.x;
    const int tid = threadIdx.x;
    float*          trig  = ws + TRIG_OFF;
    float*          res_t = ws + REST_OFF;
    unsigned short* vol_h = (unsigned short*)(ws + VOLB_OFF);
    float*          part  = ws + PART_OFF;

    // ================= Phase 1: transpose + trig + seed =================
    {
        const int y  = bid >> 2;
        const int x0 = (bid & 3) * 64;

        if (bid == 0) {
            if (tid < A) {
                float th = (float)tid * (float)(3.14159265358979323846 / (double)A);
                trig[2 * tid]     = cosf(th);
                trig[2 * tid + 1] = sinf(th);
            } else if (tid >= 2 * A) {
                trig[tid] = 0.f;            // zero the padding (absorbs -128B tap)
            }
        }

        const int xr = tid & 63;
        const int zr = tid >> 6;
        #pragma unroll
        for (int pz = 0; pz < 8; ++pz) {
            int z = pz * 4 + zr;
            smem[xr * 33 + z] = src[(z * NY + y) * NX + x0 + xr];
        }
        __syncthreads();
        const int zw = tid & 31;
        const int xw = tid >> 5;
        #pragma unroll
        for (int px = 0; px < 8; ++px) {
            int xi = px * 8 + xw;
            vol_h[(y * NX + x0 + xi) * NZ + zw] =
                __half_as_ushort(__float2half(smem[xi * 33 + zw]));
        }

        if (y < A) {
            const int a  = y;
            const int u0 = (bid & 3) * 64;
            __syncthreads();
            const int col = tid & 63;
            const int r0  = tid >> 6;
            #pragma unroll
            for (int i = 0; i < 8; ++i) {
                int r = i * 4 + r0;
                smem[r * 65 + col] = p[a * 8192 + r * 256 + u0 + col];
            }
            __syncthreads();
            const int ul = tid >> 2;
            const int zb = (tid & 3) * 8;
            float o[8];
            #pragma unroll
            for (int k = 0; k < 8; ++k) {
                int z = zb + k;
                int r = ((z & 7) << 2) + (z >> 3);
                o[k] = -smem[r * 65 + ul];
            }
            float4* d = (float4*)(res_t + (a * DET0 + u0 + ul) * NZ + zb);
            d[0] = make_float4(o[0], o[1], o[2], o[3]);
            d[1] = make_float4(o[4], o[5], o[6], o[7]);
        }
    }
    grid.sync();

    // ================= Phase 2: forward projection (3 units/block) =================
    #pragma unroll 1
    for (int u3 = 0; u3 < 3; ++u3) {
        const int unit = bid + u3 * 1024;        // 3072 units = (4 ux, 8 cid, 96 a)
        const int a   = unit >> 5;
        const int cid = (unit >> 2) & 7;
        const int ux  = unit & 3;
        const int u   = ux * 64 + (tid >> 2);
        const int zq  = tid & 3;

        const float c = trig[2 * a];
        const float s = trig[2 * a + 1];
        const float uu = (float)u - 127.5f;
        const float bx = fmaf(-uu, s, 127.5f);
        const float by = fmaf(uu, c, 127.5f);

        float lo1, hi1, lo2, hi2;
        rng(c, bx, -1.f, 256.f, lo1, hi1);
        rng(s, by, -1.f, 256.f, lo2, hi2);
        float fl = fmaxf(lo1, lo2), fh = fminf(hi1, hi2);
        int F0 = max(0,     clampi(ceilf(fl + 127.5f)));
        int F1 = min(T - 1, clampi(floorf(fh + 127.5f)));
        int len = F1 - F0 + 1; if (len < 0) len = 0;
        int b0 = F0 + (len * cid) / NC;
        int b1 = F0 + (len * (cid + 1)) / NC - 1;
        rng(c, bx, 1.f, 253.5f, lo1, hi1);
        rng(s, by, 1.f, 253.5f, lo2, hi2);
        float il = fmaxf(lo1, lo2), ih = fminf(hi1, hi2);
        int tI0 = max(clampi(ceilf(il + 127.5f)) + 1, b0);
        int tI1 = min(clampi(floorf(ih + 127.5f)) - 1, b1);
        if (tI0 > tI1) { tI0 = b1 + 1; tI1 = b1; }

        const char* base = (const char*)vol_h + zq * 16;
        float acc[8];
        #pragma unroll
        for (int k = 0; k < 8; ++k) acc[k] = 0.f;

        for (int t = b0; t < tI0; ++t) {
            float ttf = (float)t - 127.5f;
            sample_edge(base, fmaf(ttf, c, bx), fmaf(ttf, s, by), acc);
        }
        for (int t = tI0; t <= tI1; ++t) {
            float ttf = (float)t - 127.5f;
            float ix = fmaf(ttf, c, bx);
            float iy = fmaf(ttf, s, by);
            float xf = floorf(ix), yf = floorf(iy);
            float fx = ix - xf, fy = iy - yf;
            int row = ((int)yf << 8) + (int)xf;
            const char* p0 = base + ((size_t)row << 6);
            uint4 q00 = *(const uint4*)(p0);
            uint4 q01 = *(const uint4*)(p0 + 64);
            uint4 q10 = *(const uint4*)(p0 + 16384);
            uint4 q11 = *(const uint4*)(p0 + 16384 + 64);
            float wx0 = 1.f - fx, wy0 = 1.f - fy;
            acc8h(acc, q00, wy0 * wx0);
            acc8h(acc, q01, wy0 * fx);
            acc8h(acc, q10, fy * wx0);
            acc8h(acc, q11, fy * fx);
        }
        for (int t = tI1 + 1; t <= b1; ++t) {
            float ttf = (float)t - 127.5f;
            sample_edge(base, fmaf(ttf, c, bx), fmaf(ttf, s, by), acc);
        }

        float4* dst = (float4*)(part + (size_t)cid * RES_ELEMS +
                                ((a * DET0 + u) * NZ + zq * 8));
        dst[0] = make_float4(acc[0], acc[1], acc[2], acc[3]);
        dst[1] = make_float4(acc[4], acc[5], acc[6], acc[7]);
    }
    grid.sync();

    // ================= Phase 3: combine (first 768 blocks) =================
    if (bid < 768) {
        const int j4 = bid * 256 + tid;
        float4 v = ((const float4*)res_t)[j4];
        #pragma unroll
        for (int c = 0; c < NC; ++c) {
            float4 w = ((const float4*)(part + (size_t)c * RES_ELEMS))[j4];
            v.x += w.x; v.y += w.y; v.z += w.z; v.w += w.w;
        }
        ((float4*)res_t)[j4] = v;
    }
    grid.sync();

    // ================= Phase 4: backprojection (2 units/block) =================
    #pragma unroll 1
    for (int u2 = 0; u2 < 2; ++u2) {
        const int unit = bid + u2 * 1024;        // 2048 units = (8 xb, 256 y)
        const int y  = unit >> 3;
        const int xb = (unit & 7) * 32;
        const int xs = tid >> 3;
        const int zq = tid & 7;
        const char* rbase = (const char*)res_t + zq * 16;
        const float xx = (float)(xb + xs) - 127.5f;
        const float yy = (float)y - 127.5f;

        float4 acc = make_float4(0.f, 0.f, 0.f, 0.f);
        #pragma unroll 4
        for (int a = 0; a < A; ++a) {
            float cc = trig[2 * a];
            float ss = trig[2 * a + 1];
            float ub = fmaf(-xx, ss, fmaf(yy, cc, 127.5f));
            float uf = floorf(ub);
            float fu = ub - uf;
            int i0 = (int)uf;
            float w0 = ((unsigned)i0 < DET0) ? (1.f - fu) : 0.f;
            float w1 = ((unsigned)(i0 + 1) < DET0) ? fu : 0.f;
            int c1 = min(max(i0 + 1, 0), DET0);   // 0..256; tap0 row = c1-1
            int off = ((a * DET0 + c1) * NZ - NZ) << 2;
            float4 v0 = *(const float4*)(rbase + off);
            float4 v1 = *(const float4*)(rbase + off + 128);
            acc.x = fmaf(w0, v0.x, fmaf(w1, v1.x, acc.x));
            acc.y = fmaf(w0, v0.y, fmaf(w1, v1.y, acc.y));
            acc.z = fmaf(w0, v0.z, fmaf(w1, v1.z, acc.z));
            acc.w = fmaf(w0, v0.w, fmaf(w1, v1.w, acc.w));
        }

        __syncthreads();                 // smem free (prev unit's reads done)
        smem[(zq * 4 + 0) * 33 + xs] = acc.x;
        smem[(zq * 4 + 1) * 33 + xs] = acc.y;
        smem[(zq * 4 + 2) * 33 + xs] = acc.z;
        smem[(zq * 4 + 3) * 33 + xs] = acc.w;
        __syncthreads();

        const int z  = tid >> 3;
        const int x4 = (tid & 7) * 4;
        float4 o = make_float4(smem[z * 33 + x4],     smem[z * 33 + x4 + 1],
                               smem[z * 33 + x4 + 2], smem[z * 33 + x4 + 3]);
        float4* dst = (float4*)(out + (size_t)z * (NY * NX) + y * NX + xb + x4);
        *dst = make_float4(-LAMB * o.x, -LAMB * o.y, -LAMB * o.z, -LAMB * o.w);
    }
}

// ---------------------------------------------------------------------------
extern "C" void kernel_launch(void* const* d_in, const int* in_sizes, int n_in,
                              void* d_out, int out_size, void* d_ws, size_t ws_size,
                              hipStream_t stream) {
    const float* x = (const float*)d_in[0];   // (1,1,32,256,256)
    const float* p = (const float*)d_in[1];   // (1,1,384,8,256)
    float* out = (float*)d_out;               // (1,1,32,256,256)
    float* ws  = (float*)d_ws;

    void* args[] = { (void*)&x, (void*)&p, (void*)&out, (void*)&ws };
    hipLaunchCooperativeKernel((const void*)k_fused, dim3(1024), dim3(256),
                               args, 0, stream);
}

// Round 13
// 191.786 us; speedup vs baseline: 3.0169x; 3.0169x over previous
//
#include <hip/hip_runtime.h>
#include <hip/hip_fp16.h>

#define A     96
#define DET0  256
#define NZ    32
#define NY    256
#define NX    256
#define T     256
#define LAMB  0.01f

// ws layout (floats):
//   trig  : [A][2]            @ 0        (192, padded to 256; padding absorbs the
//                                         harmless -128B zero-weight tap in k_backward)
//   res_t : [A][DET0][NZ]     @ 256      (786,432) fp32, seeded -p_perm by k_transpose
//   vol_h : [NY][NX][NZ] f16  @ 786,688  (2,097,152 ushorts)
//   part  : [C][A][DET0][NZ]  @ 1,835,264
#define TRIG_OFF  0
#define REST_OFF  256
#define VOLB_OFF  786688
#define PART_OFF  1835264
#define RES_ELEMS 786432

// acc += f16half(v) * w, forced v_fma_mix_f32.
__device__ __forceinline__ void accp_mix(float& a0, float& a1, unsigned v, float w) {
    asm("v_fma_mix_f32 %0, %2, %3, %0 op_sel:[0,0,0] op_sel_hi:[1,0,0]\n\t"
        "v_fma_mix_f32 %1, %2, %3, %1 op_sel:[1,0,0] op_sel_hi:[1,0,0]"
        : "+v"(a0), "+v"(a1)
        : "v"(v), "v"(w));
}
__device__ __forceinline__ void acc8h(float* acc, uint4 q, float w) {
    accp_mix(acc[0], acc[1], q.x, w);
    accp_mix(acc[2], acc[3], q.y, w);
    accp_mix(acc[4], acc[5], q.z, w);
    accp_mix(acc[6], acc[7], q.w, w);
}

// ---------------------------------------------------------------------------
// K1: transpose vol (z,y,x) fp32 -> vol_h (y,x,z) f16; fill trig table;
//     seed res_t = -p_perm. grid (NX/64, NY), block 256
__global__ __launch_bounds__(256) void k_transpose(const float* __restrict__ src,
                                                   unsigned short* __restrict__ vol_h,
                                                   float* __restrict__ trig,
                                                   const float* __restrict__ p,
                                                   float* __restrict__ res_t) {
    __shared__ float lds[64 * 33];
    const int y   = blockIdx.y;
    const int x0  = blockIdx.x * 64;
    const int tid = threadIdx.x;

    if (blockIdx.x == 0 && y == 0 && tid < A) {
        float th = (float)tid * (float)(3.14159265358979323846 / (double)A);
        trig[2 * tid]     = cosf(th);
        trig[2 * tid + 1] = sinf(th);
    }

    const int xr = tid & 63;
    const int zr = tid >> 6;
    #pragma unroll
    for (int pz = 0; pz < 8; ++pz) {
        int z = pz * 4 + zr;
        lds[xr * 33 + z] = src[(z * NY + y) * NX + x0 + xr];
    }
    __syncthreads();
    const int zw = tid & 31;
    const int xw = tid >> 5;
    #pragma unroll
    for (int px = 0; px < 8; ++px) {
        int xi = px * 8 + xw;
        vol_h[(y * NX + x0 + xi) * NZ + zw] =
            __half_as_ushort(__float2half(lds[xi * 33 + zw]));
    }

    if (y < A) {
        const int a  = y;
        const int u0 = blockIdx.x * 64;
        __syncthreads();
        const int col = tid & 63;
        const int r0  = tid >> 6;
        #pragma unroll
        for (int i = 0; i < 8; ++i) {
            int r = i * 4 + r0;
            lds[r * 65 + col] = p[a * 8192 + r * 256 + u0 + col];
        }
        __syncthreads();
        const int ul = tid >> 2;
        const int zb = (tid & 3) * 8;
        float o[8];
        #pragma unroll
        for (int k = 0; k < 8; ++k) {
            int z = zb + k;
            int r = ((z & 7) << 2) + (z >> 3);
            o[k] = -lds[r * 65 + ul];
        }
        float4* d = (float4*)(res_t + (a * DET0 + u0 + ul) * NZ + zb);
        d[0] = make_float4(o[0], o[1], o[2], o[3]);
        d[1] = make_float4(o[4], o[5], o[6], o[7]);
    }
}

// ---------------------------------------------------------------------------
__device__ __forceinline__ void rng(float g, float b, float L, float H,
                                    float& lo, float& hi) {
    if (fabsf(g) > 1e-5f) {
        float r0 = (L - b) / g, r1 = (H - b) / g;
        lo = fminf(r0, r1); hi = fmaxf(r0, r1);
    } else {
        bool in = (b >= L && b <= H);
        lo = in ? -1e9f : 1e9f;
        hi = in ? 1e9f : -1e9f;
    }
}
__device__ __forceinline__ int clampi(float v) {
    return (int)fminf(fmaxf(v, -2.f), 258.f);
}

__device__ __forceinline__ void sample_edge(const char* base, float ix, float iy,
                                            float* acc) {
    float xf = floorf(ix), yf = floorf(iy);
    float fx = ix - xf, fy = iy - yf;
    int x0 = (int)xf, y0 = (int)yf;
    float wx0 = 1.f - fx, wx1 = fx, wy0 = 1.f - fy, wy1 = fy;
    if ((unsigned)x0 >= NX)       wx0 = 0.f;
    if ((unsigned)(x0 + 1) >= NX) wx1 = 0.f;
    if ((unsigned)y0 >= NY)       wy0 = 0.f;
    if ((unsigned)(y0 + 1) >= NY) wy1 = 0.f;
    if ((wx0 == 0.f && wx1 == 0.f) || (wy0 == 0.f && wy1 == 0.f)) return;
    int cx0 = min(max(x0, 0), NX - 1);
    int cx1 = min(max(x0 + 1, 0), NX - 1);
    int cy0 = min(max(y0, 0), NY - 1);
    int cy1 = min(max(y0 + 1, 0), NY - 1);
    uint4 q00 = *(const uint4*)(base + ((size_t)((cy0 << 8) + cx0) << 6));
    uint4 q01 = *(const uint4*)(base + ((size_t)((cy0 << 8) + cx1) << 6));
    uint4 q10 = *(const uint4*)(base + ((size_t)((cy1 << 8) + cx0) << 6));
    uint4 q11 = *(const uint4*)(base + ((size_t)((cy1 << 8) + cx1) << 6));
    acc8h(acc, q00, wy0 * wx0);
    acc8h(acc, q01, wy0 * wx1);
    acc8h(acc, q10, wy1 * wx0);
    acc8h(acc, q11, wy1 * wx1);
}

// ---------------------------------------------------------------------------
// K2: forward projection. Per-ray slicing + v_fma_mix. __launch_bounds__(256,4)
// lifts the VGPR cap (was 24 — too small to keep the 4 tap loads in flight, so
// the compiler serialized them into a 4x latency chain). unroll 2 gives the
// scheduler 8 independent loads per window. No fences (r6's mistake).
// grid (4 u-groups, C ray-slices, A), block 256
__global__ __launch_bounds__(256, 4) void k_forward(const unsigned short* __restrict__ vol_h,
                                                    const float* __restrict__ trig,
                                                    float* __restrict__ part) {
    const int tid = threadIdx.x;
    const int a   = blockIdx.z;
    const int u   = blockIdx.x * 64 + (tid >> 2);
    const int zq  = tid & 3;
    const int cid = blockIdx.y;
    const int C   = gridDim.y;

    const float c = trig[2 * a];
    const float s = trig[2 * a + 1];
    const float uu = (float)u - 127.5f;
    const float bx = fmaf(-uu, s, 127.5f);
    const float by = fmaf(uu, c, 127.5f);

    float lo1, hi1, lo2, hi2;
    rng(c, bx, -1.f, 256.f, lo1, hi1);
    rng(s, by, -1.f, 256.f, lo2, hi2);
    float fl = fmaxf(lo1, lo2), fh = fminf(hi1, hi2);
    int F0 = max(0,     clampi(ceilf(fl + 127.5f)));
    int F1 = min(T - 1, clampi(floorf(fh + 127.5f)));
    int len = F1 - F0 + 1; if (len < 0) len = 0;
    int b0 = F0 + (len * cid) / C;
    int b1 = F0 + (len * (cid + 1)) / C - 1;
    rng(c, bx, 1.f, 253.5f, lo1, hi1);
    rng(s, by, 1.f, 253.5f, lo2, hi2);
    float il = fmaxf(lo1, lo2), ih = fminf(hi1, hi2);
    int tI0 = max(clampi(ceilf(il + 127.5f)) + 1, b0);
    int tI1 = min(clampi(floorf(ih + 127.5f)) - 1, b1);
    if (tI0 > tI1) { tI0 = b1 + 1; tI1 = b1; }

    const char* base = (const char*)vol_h + zq * 16;
    float acc[8];
    #pragma unroll
    for (int k = 0; k < 8; ++k) acc[k] = 0.f;

    for (int t = b0; t < tI0; ++t) {
        float ttf = (float)t - 127.5f;
        sample_edge(base, fmaf(ttf, c, bx), fmaf(ttf, s, by), acc);
    }
    #pragma unroll 2
    for (int t = tI0; t <= tI1; ++t) {
        float ttf = (float)t - 127.5f;
        float ix = fmaf(ttf, c, bx);
        float iy = fmaf(ttf, s, by);
        float xf = floorf(ix), yf = floorf(iy);
        float fx = ix - xf, fy = iy - yf;
        int row = ((int)yf << 8) + (int)xf;
        const char* p0 = base + ((size_t)row << 6);
        uint4 q00 = *(const uint4*)(p0);
        uint4 q01 = *(const uint4*)(p0 + 64);
        uint4 q10 = *(const uint4*)(p0 + 16384);
        uint4 q11 = *(const uint4*)(p0 + 16384 + 64);
        float wx0 = 1.f - fx, wy0 = 1.f - fy;
        acc8h(acc, q00, wy0 * wx0);
        acc8h(acc, q01, wy0 * fx);
        acc8h(acc, q10, fy * wx0);
        acc8h(acc, q11, fy * fx);
    }
    for (int t = tI1 + 1; t <= b1; ++t) {
        float ttf = (float)t - 127.5f;
        sample_edge(base, fmaf(ttf, c, bx), fmaf(ttf, s, by), acc);
    }

    float4* dst = (float4*)(part + (size_t)cid * RES_ELEMS +
                            ((a * DET0 + u) * NZ + zq * 8));
    dst[0] = make_float4(acc[0], acc[1], acc[2], acc[3]);
    dst[1] = make_float4(acc[4], acc[5], acc[6], acc[7]);
}

// ---------------------------------------------------------------------------
// K3: res_t (seeded -p_perm) += sum_c part[c]. grid (768), block 256
__global__ __launch_bounds__(256) void k_combine(const float* __restrict__ part,
                                                 float* __restrict__ res_t,
                                                 int C) {
    const int j4 = blockIdx.x * 256 + threadIdx.x;
    float4 v = ((const float4*)res_t)[j4];
    for (int c = 0; c < C; ++c) {
        float4 w = ((const float4*)(part + (size_t)c * RES_ELEMS))[j4];
        v.x += w.x; v.y += w.y; v.z += w.z; v.w += w.w;
    }
    ((float4*)res_t)[j4] = v;
}

// ---------------------------------------------------------------------------
// K4: backprojection v4 (round-10 best): inline weights, 4.2 KB LDS, 8 blocks/CU.
// thread = (xs = tid>>3 of 32, zq = tid&7; 4 z per lane). grid (NX/32, NY).
// Zero-weight clamped taps may read the trig padding harmlessly (-128B stays in ws).
__global__ __launch_bounds__(256, 8) void k_backward(const float* __restrict__ res_t,
                                                     const float* __restrict__ trig,
                                                     float* __restrict__ out) {
    __shared__ float ob[32 * 33];   // 4,224 B output staging
    const int tid = threadIdx.x;
    const int y  = blockIdx.y;
    const int xb = blockIdx.x * 32;
    const int xs = tid >> 3;
    const int zq = tid & 7;          // 4 z per lane
    const char* rbase = (const char*)res_t + zq * 16;
    const float xx = (float)(xb + xs) - 127.5f;
    const float yy = (float)y - 127.5f;

    float4 acc = make_float4(0.f, 0.f, 0.f, 0.f);
    #pragma unroll 4
    for (int a = 0; a < A; ++a) {
        float cc = trig[2 * a];      // uniform -> scalar loads
        float ss = trig[2 * a + 1];
        float ub = fmaf(-xx, ss, fmaf(yy, cc, 127.5f));
        float uf = floorf(ub);
        float fu = ub - uf;
        int i0 = (int)uf;
        float w0 = ((unsigned)i0 < DET0) ? (1.f - fu) : 0.f;
        float w1 = ((unsigned)(i0 + 1) < DET0) ? fu : 0.f;
        int c1 = min(max(i0 + 1, 0), DET0);       // 0..256; tap0 row = c1-1
        int off = ((a * DET0 + c1) * NZ - NZ) << 2;
        float4 v0 = *(const float4*)(rbase + off);
        float4 v1 = *(const float4*)(rbase + off + 128);
        acc.x = fmaf(w0, v0.x, fmaf(w1, v1.x, acc.x));
        acc.y = fmaf(w0, v0.y, fmaf(w1, v1.y, acc.y));
        acc.z = fmaf(w0, v0.z, fmaf(w1, v1.z, acc.z));
        acc.w = fmaf(w0, v0.w, fmaf(w1, v1.w, acc.w));
    }

    ob[(zq * 4 + 0) * 33 + xs] = acc.x;
    ob[(zq * 4 + 1) * 33 + xs] = acc.y;
    ob[(zq * 4 + 2) * 33 + xs] = acc.z;
    ob[(zq * 4 + 3) * 33 + xs] = acc.w;
    __syncthreads();

    const int z  = tid >> 3;
    const int x4 = (tid & 7) * 4;
    float4 o = make_float4(ob[z * 33 + x4],     ob[z * 33 + x4 + 1],
                           ob[z * 33 + x4 + 2], ob[z * 33 + x4 + 3]);
    float4* dst = (float4*)(out + (size_t)z * (NY * NX) + y * NX + xb + x4);
    *dst = make_float4(-LAMB * o.x, -LAMB * o.y, -LAMB * o.z, -LAMB * o.w);
}

// ---------------------------------------------------------------------------
extern "C" void kernel_launch(void* const* d_in, const int* in_sizes, int n_in,
                              void* d_out, int out_size, void* d_ws, size_t ws_size,
                              hipStream_t stream) {
    const float* x = (const float*)d_in[0];   // (1,1,32,256,256)
    const float* p = (const float*)d_in[1];   // (1,1,384,8,256)
    float* out = (float*)d_out;               // (1,1,32,256,256)
    float* ws  = (float*)d_ws;

    float*          trig  = ws + TRIG_OFF;
    float*          res_t = ws + REST_OFF;
    unsigned short* vol_h = (unsigned short*)(ws + VOLB_OFF);
    float*          part  = ws + PART_OFF;

    size_t avail = ws_size / 4;
    int C = 8;
    while (C > 1 && (size_t)PART_OFF + (size_t)C * RES_ELEMS > avail) C >>= 1;

    k_transpose<<<dim3(NX / 64, NY), 256, 0, stream>>>(x, vol_h, trig, p, res_t);
    k_forward  <<<dim3(4, C, A), 256, 0, stream>>>(vol_h, trig, part);
    k_combine  <<<dim3(RES_ELEMS / 4 / 256), 256, 0, stream>>>(part, res_t, C);
    k_backward <<<dim3(NX / 32, NY), 256, 0, stream>>>(res_t, trig, out);
}

// Round 14
// 184.948 us; speedup vs baseline: 3.1284x; 1.0370x over previous
//
#include <hip/hip_runtime.h>
#include <hip/hip_fp16.h>

#define A     96
#define DET0  256
#define NZ    32
#define NY    256
#define NX    256
#define T     256
#define LAMB  0.01f

// ws layout (floats):
//   trig  : [A][2]            @ 0        (192, padded to 256; padding absorbs the
//                                         harmless -128B zero-weight tap in k_backward)
//   res_t : [A][DET0][NZ]     @ 256      (786,432) fp32, seeded -p_perm by k_transpose
//   vol_h : [NY][NX][NZ] f16  @ 786,688  (2,097,152 ushorts)
//   part  : [C][A][DET0][NZ]  @ 1,835,264
#define TRIG_OFF  0
#define REST_OFF  256
#define VOLB_OFF  786688
#define PART_OFF  1835264
#define RES_ELEMS 786432

// acc += f16half(v) * w, forced v_fma_mix_f32.
__device__ __forceinline__ void accp_mix(float& a0, float& a1, unsigned v, float w) {
    asm("v_fma_mix_f32 %0, %2, %3, %0 op_sel:[0,0,0] op_sel_hi:[1,0,0]\n\t"
        "v_fma_mix_f32 %1, %2, %3, %1 op_sel:[1,0,0] op_sel_hi:[1,0,0]"
        : "+v"(a0), "+v"(a1)
        : "v"(v), "v"(w));
}
__device__ __forceinline__ void acc8h(float* acc, uint4 q, float w) {
    accp_mix(acc[0], acc[1], q.x, w);
    accp_mix(acc[2], acc[3], q.y, w);
    accp_mix(acc[4], acc[5], q.z, w);
    accp_mix(acc[6], acc[7], q.w, w);
}

// ---------------------------------------------------------------------------
// K1: transpose vol (z,y,x) fp32 -> vol_h (y,x,z) f16; fill trig table;
//     seed res_t = -p_perm. grid (NX/64, NY), block 256
__global__ __launch_bounds__(256) void k_transpose(const float* __restrict__ src,
                                                   unsigned short* __restrict__ vol_h,
                                                   float* __restrict__ trig,
                                                   const float* __restrict__ p,
                                                   float* __restrict__ res_t) {
    __shared__ float lds[64 * 33];
    const int y   = blockIdx.y;
    const int x0  = blockIdx.x * 64;
    const int tid = threadIdx.x;

    if (blockIdx.x == 0 && y == 0 && tid < A) {
        float th = (float)tid * (float)(3.14159265358979323846 / (double)A);
        trig[2 * tid]     = cosf(th);
        trig[2 * tid + 1] = sinf(th);
    }

    const int xr = tid & 63;
    const int zr = tid >> 6;
    #pragma unroll
    for (int pz = 0; pz < 8; ++pz) {
        int z = pz * 4 + zr;
        lds[xr * 33 + z] = src[(z * NY + y) * NX + x0 + xr];
    }
    __syncthreads();
    const int zw = tid & 31;
    const int xw = tid >> 5;
    #pragma unroll
    for (int px = 0; px < 8; ++px) {
        int xi = px * 8 + xw;
        vol_h[(y * NX + x0 + xi) * NZ + zw] =
            __half_as_ushort(__float2half(lds[xi * 33 + zw]));
    }

    if (y < A) {
        const int a  = y;
        const int u0 = blockIdx.x * 64;
        __syncthreads();
        const int col = tid & 63;
        const int r0  = tid >> 6;
        #pragma unroll
        for (int i = 0; i < 8; ++i) {
            int r = i * 4 + r0;
            lds[r * 65 + col] = p[a * 8192 + r * 256 + u0 + col];
        }
        __syncthreads();
        const int ul = tid >> 2;
        const int zb = (tid & 3) * 8;
        float o[8];
        #pragma unroll
        for (int k = 0; k < 8; ++k) {
            int z = zb + k;
            int r = ((z & 7) << 2) + (z >> 3);
            o[k] = -lds[r * 65 + ul];
        }
        float4* d = (float4*)(res_t + (a * DET0 + u0 + ul) * NZ + zb);
        d[0] = make_float4(o[0], o[1], o[2], o[3]);
        d[1] = make_float4(o[4], o[5], o[6], o[7]);
    }
}

// ---------------------------------------------------------------------------
__device__ __forceinline__ void rng(float g, float b, float L, float H,
                                    float& lo, float& hi) {
    if (fabsf(g) > 1e-5f) {
        float r0 = (L - b) / g, r1 = (H - b) / g;
        lo = fminf(r0, r1); hi = fmaxf(r0, r1);
    } else {
        bool in = (b >= L && b <= H);
        lo = in ? -1e9f : 1e9f;
        hi = in ? 1e9f : -1e9f;
    }
}
__device__ __forceinline__ int clampi(float v) {
    return (int)fminf(fmaxf(v, -2.f), 258.f);
}

// Edge sample, 8-lane-per-u form: this lane handles column x0+col, z-slice
// (zq8&3). base16 = vol bytes + (zq8&3)*16.
__device__ __forceinline__ void sample_edge8(const char* base16, int col,
                                             float ix, float iy, float* acc) {
    float xf = floorf(ix), yf = floorf(iy);
    float fx = ix - xf, fy = iy - yf;
    int x  = (int)xf + col;
    int y0 = (int)yf;
    float wx  = col ? fx : (1.f - fx);
    float wy0 = 1.f - fy, wy1 = fy;
    if ((unsigned)x >= NX)        wx  = 0.f;
    if ((unsigned)y0 >= NY)       wy0 = 0.f;
    if ((unsigned)(y0 + 1) >= NY) wy1 = 0.f;
    if (wx == 0.f || (wy0 == 0.f && wy1 == 0.f)) return;
    int cx  = min(max(x, 0), NX - 1);
    int cy0 = min(max(y0, 0), NY - 1);
    int cy1 = min(max(y0 + 1, 0), NY - 1);
    uint4 q0 = *(const uint4*)(base16 + ((size_t)((cy0 << 8) + cx) << 6));
    uint4 q1 = *(const uint4*)(base16 + ((size_t)((cy1 << 8) + cx) << 6));
    acc8h(acc, q0, wy0 * wx);
    acc8h(acc, q1, wy1 * wx);
}

// ---------------------------------------------------------------------------
// K2: forward projection, 8-lane-per-u mapping. The x-adjacent tap pairs
// (q00|q01 and q10|q11) are CONTIGUOUS 128B in vol_h ([y][x][z] layout), so one
// wave-load covers both x-columns: lane zq8<4 gets column x, zq8>=4 column x+1
// (addr = row<<6 + zq8*16). 2 load instrs/iter instead of 4 -> ~25-50% fewer
// L1 line-requests (the measured 0.94 lines/cy/CU saturation). Columns are
// folded by one shfl_xor(4) at the end — pure reassociation, same fp32 math.
// grid (8 u-groups, C ray-slices, A), block 256 (= 32 u x 8 lanes)
__global__ __launch_bounds__(256) void k_forward(const unsigned short* __restrict__ vol_h,
                                                 const float* __restrict__ trig,
                                                 float* __restrict__ part) {
    const int tid = threadIdx.x;
    const int a   = blockIdx.z;
    const int u   = blockIdx.x * 32 + (tid >> 3);
    const int zq8 = tid & 7;                 // lane within u: col = zq8>>2, slice = zq8&3
    const int col = zq8 >> 2;
    const int cid = blockIdx.y;
    const int C   = gridDim.y;

    const float c = trig[2 * a];
    const float s = trig[2 * a + 1];
    const float uu = (float)u - 127.5f;
    const float bx = fmaf(-uu, s, 127.5f);
    const float by = fmaf(uu, c, 127.5f);

    float lo1, hi1, lo2, hi2;
    rng(c, bx, -1.f, 256.f, lo1, hi1);
    rng(s, by, -1.f, 256.f, lo2, hi2);
    float fl = fmaxf(lo1, lo2), fh = fminf(hi1, hi2);
    int F0 = max(0,     clampi(ceilf(fl + 127.5f)));
    int F1 = min(T - 1, clampi(floorf(fh + 127.5f)));
    int len = F1 - F0 + 1; if (len < 0) len = 0;
    int b0 = F0 + (len * cid) / C;
    int b1 = F0 + (len * (cid + 1)) / C - 1;
    rng(c, bx, 1.f, 253.5f, lo1, hi1);
    rng(s, by, 1.f, 253.5f, lo2, hi2);
    float il = fmaxf(lo1, lo2), ih = fminf(hi1, hi2);
    int tI0 = max(clampi(ceilf(il + 127.5f)) + 1, b0);
    int tI1 = min(clampi(floorf(ih + 127.5f)) - 1, b1);
    if (tI0 > tI1) { tI0 = b1 + 1; tI1 = b1; }

    const char* base16 = (const char*)vol_h + (zq8 & 3) * 16;  // edge path (per-col)
    const char* base2  = (const char*)vol_h + zq8 * 16;        // interior (128B pair)
    float acc[8];
    #pragma unroll
    for (int k = 0; k < 8; ++k) acc[k] = 0.f;

    for (int t = b0; t < tI0; ++t) {
        float ttf = (float)t - 127.5f;
        sample_edge8(base16, col, fmaf(ttf, c, bx), fmaf(ttf, s, by), acc);
    }
    for (int t = tI0; t <= tI1; ++t) {
        float ttf = (float)t - 127.5f;
        float ix = fmaf(ttf, c, bx);
        float iy = fmaf(ttf, s, by);
        float xf = floorf(ix), yf = floorf(iy);
        float fx = ix - xf, fy = iy - yf;
        int row = ((int)yf << 8) + (int)xf;
        const char* p0 = base2 + ((size_t)row << 6);
        uint4 q_top = *(const uint4*)(p0);            // covers q00|q01 across lanes
        uint4 q_bot = *(const uint4*)(p0 + 16384);    // covers q10|q11
        float wx = col ? fx : (1.f - fx);
        acc8h(acc, q_top, (1.f - fy) * wx);
        acc8h(acc, q_bot, fy * wx);
    }
    for (int t = tI1 + 1; t <= b1; ++t) {
        float ttf = (float)t - 127.5f;
        sample_edge8(base16, col, fmaf(ttf, c, bx), fmaf(ttf, s, by), acc);
    }

    // fold column x+1 into column x (lanes l <-> l^4 share (u, z-slice))
    #pragma unroll
    for (int k = 0; k < 8; ++k) acc[k] += __shfl_xor(acc[k], 4);

    if (col == 0) {
        float4* dst = (float4*)(part + (size_t)cid * RES_ELEMS +
                                ((a * DET0 + u) * NZ + (zq8 & 3) * 8));
        dst[0] = make_float4(acc[0], acc[1], acc[2], acc[3]);
        dst[1] = make_float4(acc[4], acc[5], acc[6], acc[7]);
    }
}

// ---------------------------------------------------------------------------
// K3: res_t (seeded -p_perm) += sum_c part[c]. grid (768), block 256
__global__ __launch_bounds__(256) void k_combine(const float* __restrict__ part,
                                                 float* __restrict__ res_t,
                                                 int C) {
    const int j4 = blockIdx.x * 256 + threadIdx.x;
    float4 v = ((const float4*)res_t)[j4];
    for (int c = 0; c < C; ++c) {
        float4 w = ((const float4*)(part + (size_t)c * RES_ELEMS))[j4];
        v.x += w.x; v.y += w.y; v.z += w.z; v.w += w.w;
    }
    ((float4*)res_t)[j4] = v;
}

// ---------------------------------------------------------------------------
// K4: backprojection v4 (round-10 best): inline weights, 4.2 KB LDS, 8 blocks/CU.
// thread = (xs = tid>>3 of 32, zq = tid&7; 4 z per lane). grid (NX/32, NY).
// Zero-weight clamped taps may read the trig padding harmlessly (-128B stays in ws).
__global__ __launch_bounds__(256, 8) void k_backward(const float* __restrict__ res_t,
                                                     const float* __restrict__ trig,
                                                     float* __restrict__ out) {
    __shared__ float ob[32 * 33];   // 4,224 B output staging
    const int tid = threadIdx.x;
    const int y  = blockIdx.y;
    const int xb = blockIdx.x * 32;
    const int xs = tid >> 3;
    const int zq = tid & 7;          // 4 z per lane
    const char* rbase = (const char*)res_t + zq * 16;
    const float xx = (float)(xb + xs) - 127.5f;
    const float yy = (float)y - 127.5f;

    float4 acc = make_float4(0.f, 0.f, 0.f, 0.f);
    #pragma unroll 4
    for (int a = 0; a < A; ++a) {
        float cc = trig[2 * a];      // uniform -> scalar loads
        float ss = trig[2 * a + 1];
        float ub = fmaf(-xx, ss, fmaf(yy, cc, 127.5f));
        float uf = floorf(ub);
        float fu = ub - uf;
        int i0 = (int)uf;
        float w0 = ((unsigned)i0 < DET0) ? (1.f - fu) : 0.f;
        float w1 = ((unsigned)(i0 + 1) < DET0) ? fu : 0.f;
        int c1 = min(max(i0 + 1, 0), DET0);       // 0..256; tap0 row = c1-1
        int off = ((a * DET0 + c1) * NZ - NZ) << 2;
        float4 v0 = *(const float4*)(rbase + off);
        float4 v1 = *(const float4*)(rbase + off + 128);
        acc.x = fmaf(w0, v0.x, fmaf(w1, v1.x, acc.x));
        acc.y = fmaf(w0, v0.y, fmaf(w1, v1.y, acc.y));
        acc.z = fmaf(w0, v0.z, fmaf(w1, v1.z, acc.z));
        acc.w = fmaf(w0, v0.w, fmaf(w1, v1.w, acc.w));
    }

    ob[(zq * 4 + 0) * 33 + xs] = acc.x;
    ob[(zq * 4 + 1) * 33 + xs] = acc.y;
    ob[(zq * 4 + 2) * 33 + xs] = acc.z;
    ob[(zq * 4 + 3) * 33 + xs] = acc.w;
    __syncthreads();

    const int z  = tid >> 3;
    const int x4 = (tid & 7) * 4;
    float4 o = make_float4(ob[z * 33 + x4],     ob[z * 33 + x4 + 1],
                           ob[z * 33 + x4 + 2], ob[z * 33 + x4 + 3]);
    float4* dst = (float4*)(out + (size_t)z * (NY * NX) + y * NX + xb + x4);
    *dst = make_float4(-LAMB * o.x, -LAMB * o.y, -LAMB * o.z, -LAMB * o.w);
}

// ---------------------------------------------------------------------------
extern "C" void kernel_launch(void* const* d_in, const int* in_sizes, int n_in,
                              void* d_out, int out_size, void* d_ws, size_t ws_size,
                              hipStream_t stream) {
    const float* x = (const float*)d_in[0];   // (1,1,32,256,256)
    const float* p = (const float*)d_in[1];   // (1,1,384,8,256)
    float* out = (float*)d_out;               // (1,1,32,256,256)
    float* ws  = (float*)d_ws;

    float*          trig  = ws + TRIG_OFF;
    float*          res_t = ws + REST_OFF;
    unsigned short* vol_h = (unsigned short*)(ws + VOLB_OFF);
    float*          part  = ws + PART_OFF;

    size_t avail = ws_size / 4;
    int C = 8;
    while (C > 1 && (size_t)PART_OFF + (size_t)C * RES_ELEMS > avail) C >>= 1;

    k_transpose<<<dim3(NX / 64, NY), 256, 0, stream>>>(x, vol_h, trig, p, res_t);
    k_forward  <<<dim3(8, C, A), 256, 0, stream>>>(vol_h, trig, part);
    k_combine  <<<dim3(RES_ELEMS / 4 / 256), 256, 0, stream>>>(part, res_t, C);
    k_backward <<<dim3(NX / 32, NY), 256, 0, stream>>>(res_t, trig, out);
}